// Round 10
// baseline (1337.684 us; speedup 1.0000x reference)
//
#include <hip/hip_runtime.h>
#include <stdint.h>

#define KVOL 27
#define CIN  32
#define COUT 64
#define RB   64          // output rows per block (6-bit rowlocal)
#define NWV  9           // waves per block: wave w owns k = 3w..3w+2
#define ENTCAP 1280      // block entry cap (mean 864, sigma 29 -> +14 sigma)
#define SCAN_CHUNK 4096

// ---------------------------------------------------------------------------
// histogram over out-major (block64, k) bins — 2 pairs per thread
// ---------------------------------------------------------------------------
__global__ __launch_bounds__(256) void hist_kernel(const int4* __restrict__ kmap2,
                                                   int* __restrict__ count, int M2) {
  int t = blockIdx.x * 256 + threadIdx.x;
  int k = blockIdx.y;
  if (t < M2) {
    int4 v = kmap2[(size_t)k * M2 + t];
    atomicAdd(&count[(v.y >> 6) * KVOL + k], 1);
    atomicAdd(&count[(v.w >> 6) * KVOL + k], 1);
  }
}

// ---------------------------------------------------------------------------
// scan (3 kernels) — verified rounds 2-9
// ---------------------------------------------------------------------------
__global__ __launch_bounds__(256) void scan_reduce(const int* __restrict__ count,
                                                   int* __restrict__ partial, int nb) {
  __shared__ int ws[4];
  int t = threadIdx.x;
  int base = blockIdx.x * SCAN_CHUNK + t * 16;
  int s = 0;
#pragma unroll
  for (int i = 0; i < 16; ++i) { int idx = base + i; if (idx < nb) s += count[idx]; }
  for (int d = 32; d; d >>= 1) s += __shfl_down(s, d);
  if ((t & 63) == 0) ws[t >> 6] = s;
  __syncthreads();
  if (t == 0) partial[blockIdx.x] = ws[0] + ws[1] + ws[2] + ws[3];
}

__global__ __launch_bounds__(64) void scan_partials(int* __restrict__ partial,
                                                    int nchunks, int* __restrict__ total_out) {
  int lane = threadIdx.x;
  int run = 0;
  for (int base = 0; base < nchunks; base += 64) {
    int i = base + lane;
    int orig = (i < nchunks) ? partial[i] : 0;
    int v = orig;
    for (int d = 1; d < 64; d <<= 1) { int u = __shfl_up(v, d); if (lane >= d) v += u; }
    if (i < nchunks) partial[i] = run + v - orig;
    run += __shfl(v, 63);
  }
  if (lane == 0) *total_out = run;
}

__global__ __launch_bounds__(256) void scan_down(const int* __restrict__ count,
                                                 const int* __restrict__ partial,
                                                 int* __restrict__ start,
                                                 int* __restrict__ cursor, int nb) {
  __shared__ int wsum[4];
  int t = threadIdx.x, blk = blockIdx.x;
  int base = blk * SCAN_CHUNK + t * 16;
  int v[16]; int s = 0;
#pragma unroll
  for (int i = 0; i < 16; ++i) { int idx = base + i; v[i] = (idx < nb) ? count[idx] : 0; s += v[i]; }
  int lane = t & 63, wv = t >> 6;
  int sv = s;
  for (int d = 1; d < 64; d <<= 1) { int u = __shfl_up(sv, d); if (lane >= d) sv += u; }
  if (lane == 63) wsum[wv] = sv;
  __syncthreads();
  int wbase = 0;
  for (int i = 0; i < wv; ++i) wbase += wsum[i];
  int prefix = partial[blk] + wbase + (sv - s);
#pragma unroll
  for (int i = 0; i < 16; ++i) {
    int idx = base + i;
    if (idx < nb) { start[idx] = prefix; cursor[idx] = prefix; }
    prefix += v[i];
  }
}

// ---------------------------------------------------------------------------
// scatter into out-major bins: entry = in_idx(18b) | rowlocal(6b)<<18
// ---------------------------------------------------------------------------
__global__ __launch_bounds__(256) void scatter_kernel(const int4* __restrict__ kmap2,
                                                      int* __restrict__ cursor,
                                                      uint32_t* __restrict__ binned, int M2) {
  int t = blockIdx.x * 256 + threadIdx.x;
  int k = blockIdx.y;
  if (t < M2) {
    int4 v = kmap2[(size_t)k * M2 + t];
    int p1 = atomicAdd(&cursor[(v.y >> 6) * KVOL + k], 1);
    binned[p1] = (uint32_t)v.x | ((uint32_t)(v.y & 63) << 18);
    int p2 = atomicAdd(&cursor[(v.w >> 6) * KVOL + k], 1);
    binned[p2] = (uint32_t)v.z | ((uint32_t)(v.w & 63) << 18);
  }
}

// ---------------------------------------------------------------------------
// main: r1's VALU-dot idiom + LDS-tile output (no global atomics, no MFMA).
// Block = 9 waves, 64 out rows, out-major bins -> block entry list is ONE
// contiguous range, burst-copied to LDS. Wave w owns k=3w..3w+2; per segment
// it holds w[32] (fp32 weights, coalesced per-lane column) and walks entries
// 2 at a time: broadcast entry word (ds_read) -> broadcast feat row (8x
// float4, one 128B line) -> two independent 32-FMA chains -> 2 fire-and-
// forget ds_add into tile[rl][lane]. 2-way LDS banks = free. One writeout.
// ---------------------------------------------------------------------------
__global__ __launch_bounds__(NWV * 64) void conv_dot(
    const float* __restrict__ feat,       // [N][CIN] f32
    const uint32_t* __restrict__ binned,  // [E] out-major
    const int* __restrict__ start,        // [NBIN+1]
    const float* __restrict__ kern,       // [KVOL][CIN][COUT] f32
    const float* __restrict__ bias,       // [COUT]
    float* __restrict__ out) {            // [N][COUT]
  __shared__ float tile[RB][COUT + 1];    // 16.6 KB, stride 65
  __shared__ uint32_t ents[ENTCAP];       // 5 KB
  const int wv = threadIdx.x >> 6;
  const int l  = threadIdx.x & 63;
  const int blk = blockIdx.x;

  // zero tile
  for (int i = threadIdx.x; i < RB * (COUT + 1); i += NWV * 64)
    ((float*)tile)[i] = 0.f;

  // block entry range (uniform scalar loads)
  const int base = start[blk * KVOL];
  int tot = start[blk * KVOL + KVOL] - base;
  if (tot > ENTCAP) tot = ENTCAP;   // statistically impossible; stay safe

  // burst-copy the block's whole entry list to LDS (coalesced)
  for (int i = threadIdx.x; i < tot; i += NWV * 64)
    ents[i] = binned[base + i];

  // my wave's segment bounds: start[blk*27 + 3wv + {0,1,2,3}]
  int sb = (l < 4) ? start[blk * KVOL + 3 * wv + l] : 0;
  int b0 = __shfl(sb, 0) - base;
  int b1 = __shfl(sb, 1) - base;
  int b2 = __shfl(sb, 2) - base;
  int b3 = __shfl(sb, 3) - base;
  if (b0 > tot) b0 = tot; if (b1 > tot) b1 = tot;
  if (b2 > tot) b2 = tot; if (b3 > tot) b3 = tot;

  __syncthreads();   // tile zeroed + ents visible

#pragma unroll
  for (int t = 0; t < 3; ++t) {
    const int k  = 3 * wv + t;
    const int lo = (t == 0) ? b0 : (t == 1) ? b1 : b2;
    const int hi = (t == 0) ? b1 : (t == 1) ? b2 : b3;
    if (hi <= lo) continue;

    // per-lane weight column for this k (coalesced: 64 lanes x 4B per i)
    float w[CIN];
    const float* wk = kern + (size_t)k * CIN * COUT + l;
#pragma unroll
    for (int i = 0; i < CIN; ++i) w[i] = wk[i * COUT];

    int m = lo;
    for (; m + 2 <= hi; m += 2) {
      uint32_t e0 = ents[m], e1 = ents[m + 1];   // broadcast ds_read
      const float4* f0 = (const float4*)(feat + (size_t)(e0 & 0x3FFFFu) * CIN);
      const float4* f1 = (const float4*)(feat + (size_t)(e1 & 0x3FFFFu) * CIN);
      float a0 = 0.f, a1 = 0.f;
#pragma unroll
      for (int j = 0; j < 8; ++j) {
        float4 v0 = f0[j];                       // broadcast: one 128B line
        float4 v1 = f1[j];
        a0 = fmaf(v0.x, w[4 * j + 0], a0);
        a0 = fmaf(v0.y, w[4 * j + 1], a0);
        a0 = fmaf(v0.z, w[4 * j + 2], a0);
        a0 = fmaf(v0.w, w[4 * j + 3], a0);
        a1 = fmaf(v1.x, w[4 * j + 0], a1);
        a1 = fmaf(v1.y, w[4 * j + 1], a1);
        a1 = fmaf(v1.z, w[4 * j + 2], a1);
        a1 = fmaf(v1.w, w[4 * j + 3], a1);
      }
      atomicAdd(&tile[(e0 >> 18) & 63][l], a0);  // fire-and-forget ds_add
      atomicAdd(&tile[(e1 >> 18) & 63][l], a1);
    }
    if (m < hi) {
      uint32_t e0 = ents[m];
      const float4* f0 = (const float4*)(feat + (size_t)(e0 & 0x3FFFFu) * CIN);
      float a0 = 0.f;
#pragma unroll
      for (int j = 0; j < 8; ++j) {
        float4 v0 = f0[j];
        a0 = fmaf(v0.x, w[4 * j + 0], a0);
        a0 = fmaf(v0.y, w[4 * j + 1], a0);
        a0 = fmaf(v0.z, w[4 * j + 2], a0);
        a0 = fmaf(v0.w, w[4 * j + 3], a0);
      }
      atomicAdd(&tile[(e0 >> 18) & 63][l], a0);
    }
  }

  __syncthreads();   // all ds_adds done

  // writeout + bias: lane = cout, 256B coalesced rows
  const float bv = bias[l];
  const int R0 = blk * RB;
  for (int r = wv; r < RB; r += NWV)
    out[(size_t)(R0 + r) * COUT + l] = tile[r][l] + bv;
}

// ---------------------------------------------------------------------------
extern "C" void kernel_launch(void* const* d_in, const int* in_sizes, int n_in,
                              void* d_out, int out_size, void* d_ws, size_t ws_size,
                              hipStream_t stream) {
  const float* feat  = (const float*)d_in[0];
  const int4*  kmap2 = (const int4*)d_in[3];   // 2 pairs per int4
  const float* kern  = (const float*)d_in[4];
  const float* bias  = (const float*)d_in[5];
  float* out = (float*)d_out;

  const int N = in_sizes[0] / CIN;            // 200000
  const int M = in_sizes[3] / (2 * KVOL);     // 100000
  const int M2 = M / 2;                       // 50000
  const int NB = N / RB;                      // 3125
  const int NBIN = NB * KVOL;                 // 84375

  // workspace (no cvt buffers needed — pure fp32 path)
  int* count   = (int*)d_ws;                            // NBIN
  int* startA  = count + NBIN;                          // NBIN+1
  int* cursor  = startA + NBIN + 1;                     // NBIN
  int* partial = cursor + NBIN;                         // 64
  uint32_t* binned = (uint32_t*)(partial + 64);         // KVOL*M

  const int nchunks = (NBIN + SCAN_CHUNK - 1) / SCAN_CHUNK;   // 21

  hipMemsetAsync(count, 0, (size_t)NBIN * sizeof(int), stream);

  dim3 pgrid((M2 + 255) / 256, KVOL);
  hipLaunchKernelGGL(hist_kernel, pgrid, dim3(256), 0, stream, kmap2, count, M2);
  hipLaunchKernelGGL(scan_reduce, dim3(nchunks), dim3(256), 0, stream, count, partial, NBIN);
  hipLaunchKernelGGL(scan_partials, dim3(1), dim3(64), 0, stream, partial, nchunks, startA + NBIN);
  hipLaunchKernelGGL(scan_down, dim3(nchunks), dim3(256), 0, stream,
                     count, partial, startA, cursor, NBIN);
  hipLaunchKernelGGL(scatter_kernel, pgrid, dim3(256), 0, stream, kmap2, cursor, binned, M2);

  hipLaunchKernelGGL(conv_dot, dim3(NB), dim3(NWV * 64), 0, stream,
                     feat, binned, startA, kern, bias, out);
}

// Round 11
// 1118.139 us; speedup vs baseline: 1.1963x; 1.1963x over previous
//
#include <hip/hip_runtime.h>
#include <stdint.h>

#define KVOL 27
#define CIN  32
#define COUT 64
#define RB   32          // output rows per block (5-bit rowlocal)
#define NWV  4           // waves per block; wave w owns k = w, w+4, ...
#define CAP  48          // bin capacity (mean 16, Poisson P(>48) ~ 1e-11)

// ---------------------------------------------------------------------------
// prep (single pass): bin-append. bin = (out>>5)*27 + k.
// pos = atomicAdd gives both the slot and, at the end, the count.
// count window is 675KB (L2-resident); binned is 32MB fixed-stride.
// ---------------------------------------------------------------------------
__global__ __launch_bounds__(256) void binapp_kernel(const int4* __restrict__ kmap2,
                                                     int* __restrict__ count,
                                                     uint32_t* __restrict__ binned,
                                                     int M2) {
  int t = blockIdx.x * 256 + threadIdx.x;
  int k = blockIdx.y;
  if (t < M2) {
    int4 v = kmap2[(size_t)k * M2 + t];
    int b1 = (v.y >> 5) * KVOL + k;
    int p1 = atomicAdd(&count[b1], 1);
    if (p1 < CAP) binned[(size_t)b1 * CAP + p1] = (uint32_t)v.x | ((uint32_t)(v.y & 31) << 18);
    int b2 = (v.w >> 5) * KVOL + k;
    int p2 = atomicAdd(&count[b2], 1);
    if (p2 < CAP) binned[(size_t)b2 * CAP + p2] = (uint32_t)v.z | ((uint32_t)(v.w & 31) << 18);
  }
}

// ---------------------------------------------------------------------------
// main: 256 threads (4 waves), 32 out rows per block -> 8 blocks/CU resident.
// Wave w owns k = w, w+4, ...; holds w[32] (fp32 weight column, lane=cout).
// Per 2 entries: uniform 8B entry load -> 2x8 broadcast float4 feat loads ->
// 8 independent 4-FMA chains (4 partial accumulators per entry, chain 32cy)
// -> 2 fire-and-forget ds_add into tile[32][65]. One writeout + bias.
// ---------------------------------------------------------------------------
__global__ __launch_bounds__(256) void conv_dot2(
    const float* __restrict__ feat,       // [N][CIN] f32
    const uint32_t* __restrict__ binned,  // [NBIN][CAP]
    const int* __restrict__ count,        // [NBIN]
    const float* __restrict__ kern,       // [KVOL][CIN][COUT] f32
    const float* __restrict__ bias,       // [COUT]
    float* __restrict__ out) {            // [N][COUT]
  __shared__ float tile[RB][COUT + 1];    // 8.4 KB, stride 65: 2-way banks
  const int wv = threadIdx.x >> 6;
  const int l  = threadIdx.x & 63;
  const int blk = blockIdx.x;

  for (int i = threadIdx.x; i < RB * (COUT + 1); i += 256)
    ((float*)tile)[i] = 0.f;
  __syncthreads();

  for (int kk = wv; kk < KVOL; kk += NWV) {
    const int bin = blk * KVOL + kk;
    int cnt = count[bin]; if (cnt > CAP) cnt = CAP;
    if (cnt <= 0) continue;
    const uint32_t* bp = binned + (size_t)bin * CAP;

    // per-lane weight column for this k (coalesced: 64 lanes x 4B)
    float w[CIN];
    const float* wk = kern + (size_t)kk * CIN * COUT + l;
#pragma unroll
    for (int i = 0; i < CIN; ++i) w[i] = wk[i * COUT];

    int m = 0;
    for (; m + 2 <= cnt; m += 2) {
      uint2 e = *(const uint2*)(bp + m);         // wave-uniform 8B load
      const float4* f0 = (const float4*)(feat + (size_t)(e.x & 0x3FFFFu) * CIN);
      const float4* f1 = (const float4*)(feat + (size_t)(e.y & 0x3FFFFu) * CIN);
      float a0[4] = {0.f, 0.f, 0.f, 0.f};
      float a1[4] = {0.f, 0.f, 0.f, 0.f};
#pragma unroll
      for (int j = 0; j < 8; ++j) {              // static idx: a[j&3] in regs
        float4 v0 = f0[j];                       // broadcast: one 128B line
        float4 v1 = f1[j];
        a0[j & 3] = fmaf(v0.x, w[4 * j + 0], a0[j & 3]);
        a0[j & 3] = fmaf(v0.y, w[4 * j + 1], a0[j & 3]);
        a0[j & 3] = fmaf(v0.z, w[4 * j + 2], a0[j & 3]);
        a0[j & 3] = fmaf(v0.w, w[4 * j + 3], a0[j & 3]);
        a1[j & 3] = fmaf(v1.x, w[4 * j + 0], a1[j & 3]);
        a1[j & 3] = fmaf(v1.y, w[4 * j + 1], a1[j & 3]);
        a1[j & 3] = fmaf(v1.z, w[4 * j + 2], a1[j & 3]);
        a1[j & 3] = fmaf(v1.w, w[4 * j + 3], a1[j & 3]);
      }
      float s0 = (a0[0] + a0[1]) + (a0[2] + a0[3]);
      float s1 = (a1[0] + a1[1]) + (a1[2] + a1[3]);
      atomicAdd(&tile[(e.x >> 18) & 31][l], s0); // fire-and-forget ds_add
      atomicAdd(&tile[(e.y >> 18) & 31][l], s1);
    }
    if (m < cnt) {
      uint32_t e0 = bp[m];
      const float4* f0 = (const float4*)(feat + (size_t)(e0 & 0x3FFFFu) * CIN);
      float a0[4] = {0.f, 0.f, 0.f, 0.f};
#pragma unroll
      for (int j = 0; j < 8; ++j) {
        float4 v0 = f0[j];
        a0[j & 3] = fmaf(v0.x, w[4 * j + 0], a0[j & 3]);
        a0[j & 3] = fmaf(v0.y, w[4 * j + 1], a0[j & 3]);
        a0[j & 3] = fmaf(v0.z, w[4 * j + 2], a0[j & 3]);
        a0[j & 3] = fmaf(v0.w, w[4 * j + 3], a0[j & 3]);
      }
      atomicAdd(&tile[(e0 >> 18) & 31][l], (a0[0] + a0[1]) + (a0[2] + a0[3]));
    }
  }

  __syncthreads();   // all ds_adds done

  // writeout + bias: lane = cout, 256B coalesced rows
  const float bv = bias[l];
  const int R0 = blk * RB;
  for (int r = wv; r < RB; r += NWV)
    out[(size_t)(R0 + r) * COUT + l] = tile[r][l] + bv;
}

// ---------------------------------------------------------------------------
extern "C" void kernel_launch(void* const* d_in, const int* in_sizes, int n_in,
                              void* d_out, int out_size, void* d_ws, size_t ws_size,
                              hipStream_t stream) {
  const float* feat  = (const float*)d_in[0];
  const int4*  kmap2 = (const int4*)d_in[3];   // 2 pairs per int4
  const float* kern  = (const float*)d_in[4];
  const float* bias  = (const float*)d_in[5];
  float* out = (float*)d_out;

  const int N = in_sizes[0] / CIN;            // 200000
  const int M = in_sizes[3] / (2 * KVOL);     // 100000
  const int M2 = M / 2;                       // 50000
  const int NB = N / RB;                      // 6250
  const int NBIN = NB * KVOL;                 // 168750

  // workspace: count 675KB + binned 32.4MB
  int* count = (int*)d_ws;                               // NBIN
  uint32_t* binned = (uint32_t*)(count + NBIN);          // NBIN*CAP

  hipMemsetAsync(count, 0, (size_t)NBIN * sizeof(int), stream);

  dim3 pgrid((M2 + 255) / 256, KVOL);
  hipLaunchKernelGGL(binapp_kernel, pgrid, dim3(256), 0, stream, kmap2, count, binned, M2);

  hipLaunchKernelGGL(conv_dot2, dim3(NB), dim3(256), 0, stream,
                     feat, binned, count, kern, bias, out);
}